// Round 10
// baseline (82.956 us; speedup 1.0000x reference)
//
#include <hip/hip_runtime.h>
#include <math.h>

// StyleGAN2 2x upsample blur (upfirdn2d, up=2, f=[1,3,3,1], gain=4).
// Separable: g=[0.25,0.75,0.75,0.25]:
//   out[2i]   = 0.25*X[i-1] + 0.75*X[i]
//   out[2i+1] = 0.75*X[i]   + 0.25*X[i+1]
//
// Wave = input row PAIR {2r, 2r+1} -> output rows 4r..4r+3. Store layout is
// line-dense (16B/lane stride): lane l owns out cols [S+4l, S+4l+4) (window
// 1) and [S+256+4l, ...) (window 2), S = row's float4 alignment shift
// (advances +1 per output row; all 4 shifts statically templated off S0).
// Feed: 8 up-front float2 loads (rows 2r-1..2r+2, 2 windows each); center
// rows reused in-register (2x -> issue-side read amp 2x, not 3x).
// All output stores are NONTEMPORAL (nt) so the 268MB write stream does not
// evict input rows from L2 between their uses.
// NB: __builtin_nontemporal_store needs a NATIVE vector type, not HIP float4.

typedef float vfloat4 __attribute__((ext_vector_type(4)));

template<int S>
__device__ __forceinline__ void hblend(float v0, float v1, float vm1,
                                       float vp0, float vp1, float q[4]) {
    if (S == 0) {
        q[0] = 0.25f*vm1 + 0.75f*v0;
        q[1] = 0.75f*v0  + 0.25f*v1;
        q[2] = 0.25f*v0  + 0.75f*v1;
        q[3] = 0.75f*v1  + 0.25f*vp0;
    } else if (S == 1) {
        q[0] = 0.75f*v0  + 0.25f*v1;
        q[1] = 0.25f*v0  + 0.75f*v1;
        q[2] = 0.75f*v1  + 0.25f*vp0;
        q[3] = 0.25f*v1  + 0.75f*vp0;
    } else if (S == 2) {
        q[0] = 0.25f*v0  + 0.75f*v1;
        q[1] = 0.75f*v1  + 0.25f*vp0;
        q[2] = 0.25f*v1  + 0.75f*vp0;
        q[3] = 0.75f*vp0 + 0.25f*vp1;
    } else {
        q[0] = 0.75f*v1  + 0.25f*vp0;
        q[1] = 0.25f*v1  + 0.75f*vp0;
        q[2] = 0.75f*vp0 + 0.25f*vp1;
        q[3] = 0.25f*vp0 + 0.75f*vp1;
    }
}

template<int S>
__device__ __forceinline__ void store_row(float* __restrict__ rp, int lane,
                                          int Wo, const float q1[4],
                                          const float q2[4],
                                          float v0lane, float v1lane) {
    vfloat4 w1 = {q1[0], q1[1], q1[2], q1[3]};
    __builtin_nontemporal_store(w1, (vfloat4*)(rp + S + 4 * lane));
    int c0 = S + 256 + 4 * lane;
    if (c0 + 3 < Wo) {
        vfloat4 w2 = {q2[0], q2[1], q2[2], q2[3]};
        __builtin_nontemporal_store(w2, (vfloat4*)(rp + c0));
    } else {
        if (c0     < Wo) __builtin_nontemporal_store(q2[0], rp + c0);
        if (c0 + 1 < Wo) __builtin_nontemporal_store(q2[1], rp + c0 + 1);
        if (c0 + 2 < Wo) __builtin_nontemporal_store(q2[2], rp + c0 + 2);
        if (c0 + 3 < Wo) __builtin_nontemporal_store(q2[3], rp + c0 + 3);
    }
    if (S > 0 && lane == 0) {   // fringe cols [0,S): v[-1] contributes 0
        __builtin_nontemporal_store(0.75f * v0lane, rp);
        if (S > 1) __builtin_nontemporal_store(0.75f * v0lane + 0.25f * v1lane, rp + 1);
        if (S > 2) __builtin_nontemporal_store(0.25f * v0lane + 0.75f * v1lane, rp + 2);
    }
}

// One input row i -> output rows {orow, orow+1}. a,b,c = rows i-1, i, i+1
// (windows 1 and 2). w0/wp are the folded row-boundary masks.
template<int SE>
__device__ __forceinline__ void emit_pair(
    float2 a1, float2 b1, float2 c1, float2 a2, float2 b2, float2 c2,
    float w0, float wp, float* __restrict__ out, size_t be,
    int lane, int orow, int Ho, int Wo) {
    constexpr int SO = (SE + 1) & 3;

    float ve10 = w0*a1.x + 0.75f*b1.x, ve11 = w0*a1.y + 0.75f*b1.y;
    float ve20 = w0*a2.x + 0.75f*b2.x, ve21 = w0*a2.y + 0.75f*b2.y;
    float vo10 = 0.75f*b1.x + wp*c1.x, vo11 = 0.75f*b1.y + wp*c1.y;
    float vo20 = 0.75f*b2.x + wp*c2.x, vo21 = 0.75f*b2.y + wp*c2.y;

    float t;
    float vm1e1 = __shfl_up(ve11, 1);   if (lane == 0)  vm1e1 = 0.f;
    float vp0e1 = __shfl_down(ve10, 1);
    t = __shfl(ve20, 0);                if (lane == 63) vp0e1 = t;
    float vp1e1 = __shfl_down(ve11, 1);
    t = __shfl(ve21, 0);                if (lane == 63) vp1e1 = t;
    float vm1e2 = __shfl_up(ve21, 1);
    t = __shfl(ve11, 63);               if (lane == 0)  vm1e2 = t;
    float vp0e2 = __shfl_down(ve20, 1); if (lane == 63) vp0e2 = 0.f;
    float vp1e2 = __shfl_down(ve21, 1); if (lane == 63) vp1e2 = 0.f;
    float vm1o1 = __shfl_up(vo11, 1);   if (lane == 0)  vm1o1 = 0.f;
    float vp0o1 = __shfl_down(vo10, 1);
    t = __shfl(vo20, 0);                if (lane == 63) vp0o1 = t;
    float vp1o1 = __shfl_down(vo11, 1);
    t = __shfl(vo21, 0);                if (lane == 63) vp1o1 = t;
    float vm1o2 = __shfl_up(vo21, 1);
    t = __shfl(vo11, 63);               if (lane == 0)  vm1o2 = t;
    float vp0o2 = __shfl_down(vo20, 1); if (lane == 63) vp0o2 = 0.f;
    float vp1o2 = __shfl_down(vo21, 1); if (lane == 63) vp1o2 = 0.f;

    float q1[4], q2[4];
    float* re = out + be;
    hblend<SE>(ve10, ve11, vm1e1, vp0e1, vp1e1, q1);
    hblend<SE>(ve20, ve21, vm1e2, vp0e2, vp1e2, q2);
    store_row<SE>(re, lane, Wo, q1, q2, ve10, ve11);

    if (orow + 1 < Ho) {
        float* ro = re + Wo;
        hblend<SO>(vo10, vo11, vm1o1, vp0o1, vp1o1, q1);
        hblend<SO>(vo20, vo21, vm1o2, vp0o2, vp1o2, q2);
        store_row<SO>(ro, lane, Wo, q1, q2, vo10, vo11);
    }
}

__global__ __launch_bounds__(256) void blur_up2_kernel(
    const float* __restrict__ x, float* __restrict__ out,
    int H, int W, int Ho, int Wo) {
    int lane = threadIdx.x;                   // 0..63
    int r = blockIdx.y * 4 + threadIdx.y;     // 0..127: input rows {2r, 2r+1}
    int nc = blockIdx.z;
    int i0 = 2 * r, i1 = 2 * r + 1;

    const float* xp = x + (size_t)nc * H * W;
    const float2* prm = (const float2*)(xp + (i0 > 0 ? i0 - 1 : 0) * W);
    const float2* pr0 = (const float2*)(xp + i0 * W);
    const float2* pr1 = (const float2*)(xp + i1 * W);
    const float2* prp = (const float2*)(xp + (i1 < H - 1 ? i1 + 1 : H - 1) * W);

    // 8 up-front loads (full MLP)
    float2 m1 = prm[lane], m2 = prm[64 + lane];
    float2 z01 = pr0[lane], z02 = pr0[64 + lane];
    float2 z11 = pr1[lane], z12 = pr1[64 + lane];
    float2 p1 = prp[lane], p2 = prp[64 + lane];

    float w_top = (i0 > 0)     ? 0.25f : 0.0f;
    float w_bot = (i1 < H - 1) ? 0.25f : 0.0f;

    size_t obase = (size_t)nc * Ho * Wo;
    size_t be0 = obase + (size_t)(2 * i0) * Wo;   // output row 4r
    size_t be1 = be0 + 2 * (size_t)Wo;            // output row 4r+2
    int S0 = (int)((4 - (be0 & 3)) & 3);          // wave-uniform

    switch (S0) {
        case 0:
            emit_pair<0>(m1, z01, z11, m2, z02, z12, w_top, 0.25f, out, be0, lane, 2*i0, Ho, Wo);
            emit_pair<2>(z01, z11, p1, z02, z12, p2, 0.25f, w_bot, out, be1, lane, 2*i1, Ho, Wo);
            break;
        case 1:
            emit_pair<1>(m1, z01, z11, m2, z02, z12, w_top, 0.25f, out, be0, lane, 2*i0, Ho, Wo);
            emit_pair<3>(z01, z11, p1, z02, z12, p2, 0.25f, w_bot, out, be1, lane, 2*i1, Ho, Wo);
            break;
        case 2:
            emit_pair<2>(m1, z01, z11, m2, z02, z12, w_top, 0.25f, out, be0, lane, 2*i0, Ho, Wo);
            emit_pair<0>(z01, z11, p1, z02, z12, p2, 0.25f, w_bot, out, be1, lane, 2*i1, Ho, Wo);
            break;
        default:
            emit_pair<3>(m1, z01, z11, m2, z02, z12, w_top, 0.25f, out, be0, lane, 2*i0, Ho, Wo);
            emit_pair<1>(z01, z11, p1, z02, z12, p2, 0.25f, w_bot, out, be1, lane, 2*i1, Ho, Wo);
            break;
    }
}

extern "C" void kernel_launch(void* const* d_in, const int* in_sizes, int n_in,
                              void* d_out, int out_size, void* d_ws, size_t ws_size,
                              hipStream_t stream) {
    const float* x = (const float*)d_in[0];
    float* out = (float*)d_out;

    const int H = 256, W = 256;
    int NC = in_sizes[0] / (H * W);  // 256

    int hw_out = out_size / NC;
    int Wo = (int)(sqrt((double)hw_out) + 0.5);
    int Ho = hw_out / Wo;

    dim3 block(64, 4);
    dim3 grid(1, 32, NC);   // 128 row-pairs / 4 per block
    blur_up2_kernel<<<grid, block, 0, stream>>>(x, out, H, W, Ho, Wo);
}